// Round 16
// baseline (458.566 us; speedup 1.0000x reference)
//
#include <hip/hip_runtime.h>
#include <hip/hip_bf16.h>
#include <hip/hip_fp16.h>
#include <math.h>

// GNN: 3-layer GCN + BN + GELU + residual + meanpool + MLP -> scalar.
// R16: R15 (319us) + fp16 intermediate buffers H/A1. agg was writing fp32 H
// (50MB) that mgemm re-read fp32 (50MB) just to convert to fp16 for MFMA;
// norm_pool re-read fp32 H3. All now fp16 (BN stats still taken from the
// pre-rounding fp32 values in the epilogues). ~150MB less traffic.
// Gather loop / CSR build / MFMA / spread-atomic stats unchanged.

typedef _Float16 f16x8 __attribute__((ext_vector_type(8)));
typedef _Float16 f16x4 __attribute__((ext_vector_type(4)));
typedef float f32x4 __attribute__((ext_vector_type(4)));

__device__ __forceinline__ float gelu_f(float x) {
    return 0.5f * x * (1.0f + erff(x * 0.7071067811865476f));
}

__device__ __forceinline__ int wave_incl_scan(int v, int lane) {
#pragma unroll
    for (int off = 1; off < 64; off <<= 1) {
        int t = __shfl_up(v, (unsigned)off, 64);
        if (lane >= off) v += t;
    }
    return v;
}

__device__ __forceinline__ void load8h(const __half* __restrict__ p, float* f) {
    uint4 u = *(const uint4*)p;
    const __half2* h2p = (const __half2*)&u;
#pragma unroll
    for (int i = 0; i < 4; i++) {
        float2 t = __half22float2(h2p[i]);
        f[2 * i] = t.x;
        f[2 * i + 1] = t.y;
    }
}

__device__ __forceinline__ void acc8h(const uint4& u, float* f) {
    const __half2* h2p = (const __half2*)&u;
#pragma unroll
    for (int i = 0; i < 4; i++) {
        float2 t = __half22float2(h2p[i]);
        f[2 * i] += t.x;
        f[2 * i + 1] += t.y;
    }
}

__device__ __forceinline__ uint4 pack8h(const float* f) {
    __half2 h[4];
#pragma unroll
    for (int i = 0; i < 4; i++) h[i] = __floats2half2_rn(f[2 * i], f[2 * i + 1]);
    return *(uint4*)h;
}

// ---- init: zero double accumulators + bucket counters ----
__global__ void init_kernel(double* __restrict__ dbls, int ndbl, int* __restrict__ bucketCnt) {
    int i = blockIdx.x * 256 + threadIdx.x;
    if (i < ndbl) dbls[i] = 0.0;
    if (i < 512) bucketCnt[i] = 0;
}

// ---- CSR step 1: coarse per-bucket edge counts (LDS histogram) ----
#define EPB 8192
__global__ __launch_bounds__(512) void coarse_count_kernel(const int* __restrict__ col,
                                                           int* __restrict__ bucketCnt,
                                                           int E, int nbuckets) {
    __shared__ int cnt[512];
    for (int b = threadIdx.x; b < nbuckets; b += 512) cnt[b] = 0;
    __syncthreads();
    int e0 = blockIdx.x * EPB;
    int eend = e0 + EPB;
    if (eend > E) eend = E;
    for (int e = e0 + threadIdx.x; e < eend; e += 512)
        atomicAdd(&cnt[col[e] >> 8], 1);
    __syncthreads();
    for (int b = threadIdx.x; b < nbuckets; b += 512) {
        int c = cnt[b];
        if (c) atomicAdd(&bucketCnt[b], c);
    }
}

// ---- CSR step 2: exclusive scan of bucket counts -> bases; init bcur ----
__global__ __launch_bounds__(512) void bucket_scan_kernel(const int* __restrict__ bucketCnt,
                                                          int* __restrict__ bucketBase,
                                                          int* __restrict__ bcur,
                                                          int nbuckets, int E) {
    int lane = threadIdx.x & 63;
    int wid = threadIdx.x >> 6;
    int v = (threadIdx.x < nbuckets) ? bucketCnt[threadIdx.x] : 0;
    int incl = wave_incl_scan(v, lane);
    __shared__ int ws[8];
    if (lane == 63) ws[wid] = incl;
    __syncthreads();
    if (threadIdx.x == 0) {
        int a = 0;
#pragma unroll
        for (int j = 0; j < 8; j++) { int t = ws[j]; ws[j] = a; a += t; }
    }
    __syncthreads();
    int excl = incl - v + ws[wid];
    if (threadIdx.x < nbuckets) {
        bucketBase[threadIdx.x] = excl;
        bcur[threadIdx.x] = excl;
    }
    if (threadIdx.x == 0) bucketBase[nbuckets] = E;
}

// ---- CSR step 3: LDS-binned stage. One global atomic per (block,bucket). ----
__global__ __launch_bounds__(512) void binstage_kernel(const int* __restrict__ row,
                                                       const int* __restrict__ col,
                                                       int* __restrict__ bcur,
                                                       unsigned int* __restrict__ stage,
                                                       int E, int nbuckets) {
    __shared__ int cnt[512];
    __shared__ int gbase[512];
    int e0 = blockIdx.x * EPB;
    int eend = e0 + EPB;
    if (eend > E) eend = E;
    for (int b = threadIdx.x; b < nbuckets; b += 512) cnt[b] = 0;
    __syncthreads();
    for (int e = e0 + threadIdx.x; e < eend; e += 512)
        atomicAdd(&cnt[col[e] >> 8], 1);
    __syncthreads();
    for (int b = threadIdx.x; b < nbuckets; b += 512) {
        int c = cnt[b];
        gbase[b] = c ? atomicAdd(&bcur[b], c) : 0;
        cnt[b] = 0;  // reuse as local cursor
    }
    __syncthreads();
    for (int e = e0 + threadIdx.x; e < eend; e += 512) {
        int c = col[e];
        int b = c >> 8;
        int lp = atomicAdd(&cnt[b], 1);
        stage[gbase[b] + lp] = ((unsigned int)row[e] << 8) | (unsigned int)(c & 255);
    }
}

// ---- CSR step 4: per-bucket degrees (coalesced deg/dinv/offs) + csr fill ----
__global__ __launch_bounds__(256) void bucket_finalize_kernel(const unsigned int* __restrict__ stage,
                                                              const int* __restrict__ bucketBase,
                                                              float* __restrict__ deg,
                                                              float* __restrict__ dinv,
                                                              int* __restrict__ offs,
                                                              int* __restrict__ csr,
                                                              int N) {
    __shared__ int cnt[256];
    __shared__ int loc[256];
    __shared__ int ws[4];
    int b = blockIdx.x;
    int nb0 = b << 8;
    int base = bucketBase[b];
    int end = bucketBase[b + 1];
    cnt[threadIdx.x] = 0;
    __syncthreads();
    int m = end - base;
    for (int t = threadIdx.x; t < m; t += 256)
        atomicAdd(&cnt[stage[base + t] & 255], 1);
    __syncthreads();
    int c = cnt[threadIdx.x];
    int lane = threadIdx.x & 63;
    int wid = threadIdx.x >> 6;
    int incl = wave_incl_scan(c, lane);
    if (lane == 63) ws[wid] = incl;
    __syncthreads();
    if (threadIdx.x == 0) {
        int a = 0;
#pragma unroll
        for (int j = 0; j < 4; j++) { int t = ws[j]; ws[j] = a; a += t; }
    }
    __syncthreads();
    int excl = incl - c + ws[wid];
    int node = nb0 + threadIdx.x;
    if (node < N) {
        float d = (float)(c + 1);
        deg[node] = d;
        dinv[node] = 1.0f / sqrtf(d);
        offs[node] = base + excl;
    }
    loc[threadIdx.x] = excl;
    __syncthreads();
    for (int t = threadIdx.x; t < m; t += 256) {
        unsigned int v = stage[base + t];
        int lc = v & 255;
        int src = (int)(v >> 8);
        int pos = atomicAdd(&loc[lc], 1);
        csr[base + pos] = src;
    }
}

// ---- convert x[N][64] fp32 -> xh[N][64] fp16, scaled by dinv[node] ----
__global__ __launch_bounds__(256) void halfconv_kernel(const float* __restrict__ x,
                                                       const float* __restrict__ dinv,
                                                       __half* __restrict__ xh, int N) {
    int t = blockIdx.x * 256 + threadIdx.x;   // one 8-float chunk per thread
    if (t >= N * 8) return;
    int node = t >> 3;
    float dv = dinv[node];
    const float4* p = (const float4*)(x + (size_t)t * 8);
    float4 a = p[0], b = p[1];
    __half2 h[4];
    h[0] = __floats2half2_rn(a.x * dv, a.y * dv);
    h[1] = __floats2half2_rn(a.z * dv, a.w * dv);
    h[2] = __floats2half2_rn(b.x * dv, b.y * dv);
    h[3] = __floats2half2_rn(b.z * dv, b.w * dv);
    *(uint4*)(xh + (size_t)t * 8) = *(uint4*)h;
}

// ---- convert W[DIN][DOUT] fp32 -> fragment-ordered fp16 Wf ----
template <int DIN, int DOUT>
__global__ void wconv_kernel(const float* __restrict__ W, _Float16* __restrict__ Wf) {
    int i = blockIdx.x * 256 + threadIdx.x;
    if (i >= DIN * DOUT) return;
    int k = i / DOUT, col = i - k * DOUT;
    int s = k >> 5, krem = k & 31;
    int lg = krem >> 3, j = krem & 7;
    int t = col >> 4, c = col & 15;
    constexpr int NT = DOUT / 16;
    int l = lg * 16 + c;
    Wf[((size_t)(s * NT + t) * 64 + l) * 8 + j] = (_Float16)W[(size_t)k * DOUT + col];
}

// ---- aggregation: H[i][D] = dinv_i*(Ut[i] + sum in-edge Ut[src]) (+bias) ----
// fp16 in, fp32 accumulate, fp16 out; stats from pre-rounding fp32.
template <int D, bool STATS, bool BIAS>
__global__ __launch_bounds__(256) void agg_kernel(const __half* __restrict__ Ut,
                                                  const int* __restrict__ csr,
                                                  const int* __restrict__ offs,
                                                  const float* __restrict__ deg,
                                                  const float* __restrict__ dinv,
                                                  const float* __restrict__ bias,
                                                  __half* __restrict__ H,
                                                  double* __restrict__ tmp, int n) {
    constexpr int GPN = D / 8;
    constexpr int NPB = 256 / GPN;
    int g = threadIdx.x / GPN;
    int cl = threadIdx.x % GPN;
    int node = blockIdx.x * NPB + g;
    bool act = node < n;

    float a[8], b[8];
#pragma unroll
    for (int c = 0; c < 8; c++) { a[c] = 0.f; b[c] = 0.f; }

    int start = 0, cnt = 0;
    float dvi = 0.f;
    if (act) {
        start = offs[node];
        cnt = (int)deg[node] - 1;
        dvi = dinv[node];
        load8h(Ut + (size_t)node * D + cl * 8, a);   // self loop (pre-scaled)
    }
    const __half* __restrict__ base = Ut + cl * 8;
    int j = 0;
    for (; j + 4 <= cnt; j += 4) {
        int s0 = csr[start + j];
        int s1 = csr[start + j + 1];
        int s2 = csr[start + j + 2];
        int s3 = csr[start + j + 3];
        uint4 u0 = *(const uint4*)(base + (size_t)s0 * D);
        uint4 u1 = *(const uint4*)(base + (size_t)s1 * D);
        uint4 u2 = *(const uint4*)(base + (size_t)s2 * D);
        uint4 u3 = *(const uint4*)(base + (size_t)s3 * D);
        acc8h(u0, a);
        acc8h(u1, b);
        acc8h(u2, a);
        acc8h(u3, b);
    }
    if (j + 2 <= cnt) {
        int s0 = csr[start + j];
        int s1 = csr[start + j + 1];
        uint4 u0 = *(const uint4*)(base + (size_t)s0 * D);
        uint4 u1 = *(const uint4*)(base + (size_t)s1 * D);
        acc8h(u0, a);
        acc8h(u1, b);
        j += 2;
    }
    if (j < cnt) {
        int s0 = csr[start + j];
        uint4 u0 = *(const uint4*)(base + (size_t)s0 * D);
        acc8h(u0, a);
    }

    float h[8];
#pragma unroll
    for (int c = 0; c < 8; c++) h[c] = (a[c] + b[c]) * dvi;
    if (BIAS) {
#pragma unroll
        for (int c = 0; c < 8; c++) h[c] += bias[cl * 8 + c];
    }
    if (act) {
        *(uint4*)(H + (size_t)node * D + cl * 8) = pack8h(h);
    } else {
#pragma unroll
        for (int c = 0; c < 8; c++) h[c] = 0.f;   // no stats contribution
    }

    if constexpr (STATS) {
        float s[8], q[8];
#pragma unroll
        for (int c = 0; c < 8; c++) { s[c] = h[c]; q[c] = h[c] * h[c]; }
#pragma unroll
        for (int m = GPN; m < 64; m <<= 1) {
#pragma unroll
            for (int c = 0; c < 8; c++) {
                s[c] += __shfl_xor(s[c], m, 64);
                q[c] += __shfl_xor(q[c], m, 64);
            }
        }
        __shared__ float ps[4][GPN][8], pq[4][GPN][8];
        int wid = threadIdx.x >> 6;
        int lane = threadIdx.x & 63;
        if (lane < GPN) {
#pragma unroll
            for (int c = 0; c < 8; c++) { ps[wid][lane][c] = s[c]; pq[wid][lane][c] = q[c]; }
        }
        __syncthreads();
        if (threadIdx.x < D) {
            int cgi = threadIdx.x >> 3, ci = threadIdx.x & 7;
            float t1 = ps[0][cgi][ci] + ps[1][cgi][ci] + ps[2][cgi][ci] + ps[3][cgi][ci];
            float t2 = pq[0][cgi][ci] + pq[1][cgi][ci] + pq[2][cgi][ci] + pq[3][cgi][ci];
            int cp = (blockIdx.x & 63) * 2 * D;
            atomicAdd(&tmp[cp + threadIdx.x], (double)t1);
            atomicAdd(&tmp[cp + D + threadIdx.x], (double)t2);
        }
    }
}

// ---- MFMA GEMM: Out[n][DOUT] = f(Hin)[n][DIN] @ W (+bias)(*dinv) ----
// Hin fp16 row-major; BNIN applies scale/shift+GELU (fp32 math) in staging.
template <int DIN, int DOUT, bool BNIN, bool BIAS, bool DINVOUT, bool HALFOUT, bool STATS>
__global__ __launch_bounds__(256) void mgemm_kernel(const __half* __restrict__ Hin,
                                                    const _Float16* __restrict__ Wf,
                                                    const float* __restrict__ scale,
                                                    const float* __restrict__ shift,
                                                    const float* __restrict__ bias,
                                                    const float* __restrict__ dinv,
                                                    void* __restrict__ Out,
                                                    double* __restrict__ tmp, int n) {
    constexpr int NT = DOUT / 16;   // n-tiles per wave
    constexpr int NS = DIN / 32;    // k-steps
    constexpr int DP = DIN + 8;     // padded LDS row (halfs), keeps 16B align
    __shared__ _Float16 Hs[64 * DP];

    int node0 = blockIdx.x * 64;
    int nv = n - node0;
    if (nv > 64) nv = 64;

    // stage H tile (fp16 -> fp32 BN+GELU -> fp16 LDS), zero-pad invalid rows
    constexpr int C8R = DIN / 8;
    for (int f = threadIdx.x; f < 64 * C8R; f += 256) {
        int nn = f / C8R, k8 = f - nn * C8R;
        float v[8];
        if (nn < nv) {
            load8h(Hin + (size_t)(node0 + nn) * DIN + k8 * 8, v);
        } else {
#pragma unroll
            for (int c = 0; c < 8; c++) v[c] = 0.f;
        }
        if (BNIN && nn < nv) {
            float4 sc0 = *(const float4*)(scale + k8 * 8);
            float4 sc1 = *(const float4*)(scale + k8 * 8 + 4);
            float4 sh0 = *(const float4*)(shift + k8 * 8);
            float4 sh1 = *(const float4*)(shift + k8 * 8 + 4);
            v[0] = gelu_f(fmaf(v[0], sc0.x, sh0.x));
            v[1] = gelu_f(fmaf(v[1], sc0.y, sh0.y));
            v[2] = gelu_f(fmaf(v[2], sc0.z, sh0.z));
            v[3] = gelu_f(fmaf(v[3], sc0.w, sh0.w));
            v[4] = gelu_f(fmaf(v[4], sc1.x, sh1.x));
            v[5] = gelu_f(fmaf(v[5], sc1.y, sh1.y));
            v[6] = gelu_f(fmaf(v[6], sc1.z, sh1.z));
            v[7] = gelu_f(fmaf(v[7], sc1.w, sh1.w));
        }
        f16x8 h;
#pragma unroll
        for (int c = 0; c < 8; c++) h[c] = (_Float16)v[c];
        *(f16x8*)(&Hs[nn * DP + k8 * 8]) = h;
    }
    __syncthreads();

    int wv = threadIdx.x >> 6;
    int l = threadIdx.x & 63;
    int arow = l & 15, agrp = l >> 4;

    f32x4 acc[NT];
#pragma unroll
    for (int t = 0; t < NT; t++) acc[t] = (f32x4){0.f, 0.f, 0.f, 0.f};

    const _Float16* hrow = &Hs[(wv * 16 + arow) * DP];
#pragma unroll
    for (int s = 0; s < NS; s++) {
        f16x8 a = *(const f16x8*)(hrow + s * 32 + agrp * 8);
        const _Float16* wb = Wf + (size_t)s * NT * 512 + l * 8;
#pragma unroll
        for (int t = 0; t < NT; t++) {
            f16x8 b = *(const f16x8*)(wb + (size_t)t * 512);
            acc[t] = __builtin_amdgcn_mfma_f32_16x16x32_f16(a, b, acc[t], 0, 0, 0);
        }
    }

    int rbase = wv * 16 + agrp * 4;
    float dv4[4] = {1.f, 1.f, 1.f, 1.f};
    if (DINVOUT) {
#pragma unroll
        for (int r = 0; r < 4; r++)
            if (rbase + r < nv) dv4[r] = dinv[node0 + rbase + r];
    }
    float sa[NT], qa[NT];
#pragma unroll
    for (int t = 0; t < NT; t++) {
        int col = t * 16 + arow;
        float bcol = BIAS ? bias[col] : 0.f;
        float ssum = 0.f, qsum = 0.f;
#pragma unroll
        for (int r = 0; r < 4; r++) {
            int nn = rbase + r;
            bool valid = nn < nv;
            float v = acc[t][r];
            if (DINVOUT) v *= dv4[r];
            v += bcol;
            v = valid ? v : 0.f;
            if (valid) {
                size_t oi = (size_t)(node0 + nn) * DOUT + col;
                if (HALFOUT) ((__half*)Out)[oi] = __float2half(v);
                else ((__half*)Out)[oi] = __float2half(v);
            }
            ssum += v;
            qsum += v * v;
        }
        sa[t] = ssum;
        qa[t] = qsum;
    }

    if constexpr (STATS) {
        __shared__ float ps[4][DOUT], pq[4][DOUT];
#pragma unroll
        for (int t = 0; t < NT; t++) {
            float s = sa[t], q = qa[t];
            s += __shfl_xor(s, 16, 64); q += __shfl_xor(q, 16, 64);
            s += __shfl_xor(s, 32, 64); q += __shfl_xor(q, 32, 64);
            if (l < 16) { ps[wv][t * 16 + l] = s; pq[wv][t * 16 + l] = q; }
        }
        __syncthreads();
        if (threadIdx.x < DOUT) {
            float t1 = ps[0][threadIdx.x] + ps[1][threadIdx.x] +
                       ps[2][threadIdx.x] + ps[3][threadIdx.x];
            float t2 = pq[0][threadIdx.x] + pq[1][threadIdx.x] +
                       pq[2][threadIdx.x] + pq[3][threadIdx.x];
            int cp = (blockIdx.x & 63) * 2 * DOUT;
            atomicAdd(&tmp[cp + threadIdx.x], (double)t1);
            atomicAdd(&tmp[cp + DOUT + threadIdx.x], (double)t2);
        }
    }
}

// ---- fold 64 tmp copies -> per-channel scale/shift floats ----
template <int D>
__global__ void finalize_tmp_kernel(const double* __restrict__ tmp,
                                    const float* __restrict__ g, const float* __restrict__ be,
                                    float* __restrict__ scale, float* __restrict__ shift, int n) {
    int c = threadIdx.x;
    if (c < D) {
        double s = 0.0, q = 0.0;
        for (int gg = 0; gg < 64; gg++) {
            s += tmp[gg * 2 * D + c];
            q += tmp[gg * 2 * D + D + c];
        }
        double mu = s / n;
        double var = q / n - mu * mu;
        double inv = 1.0 / sqrt(var + 1e-5);
        double sc = (double)g[c] * inv;
        scale[c] = (float)sc;
        shift[c] = (float)((double)be[c] - mu * sc);
    }
}

// ---- fold 64 tmp copies -> raw stats sums (for norm_pool) ----
template <int D>
__global__ void combine_kernel(const double* __restrict__ tmp, double* __restrict__ stats) {
    int t = threadIdx.x;
    if (t < 2 * D) {
        double s = 0.0;
        for (int gg = 0; gg < 64; gg++) s += tmp[gg * 2 * D + t];
        stats[t] = s;
    }
}

// ---- layer-3: BN normalize + GELU + residual(x) + mean-pool accumulate ----
__global__ __launch_bounds__(256) void norm_pool_kernel(const __half* __restrict__ X3,
                                                        const float* __restrict__ x0,
                                                        const double* __restrict__ stats,
                                                        const float* __restrict__ gw,
                                                        const float* __restrict__ be,
                                                        double* __restrict__ pool, int n) {
    constexpr int D = 64;
    constexpr int RPB = 4;
    int c8 = threadIdx.x & 7;     // 8 channels per thread
    int r0 = threadIdx.x >> 3;    // 32 rows per block pass
    float sc[8], sh[8];
#pragma unroll
    for (int c = 0; c < 8; c++) {
        int ch = c8 * 8 + c;
        double mu = stats[ch] / n;
        double var = stats[ch + D] / n - mu * mu;
        double inv = 1.0 / sqrt(var + 1e-5);
        sc[c] = (float)((double)gw[ch] * inv);
        sh[c] = (float)((double)be[ch] - mu * (double)gw[ch] * inv);
    }
    int rowsPerGrid = gridDim.x * 32;
    double s[1] = {0.0};
    float acc[8];
#pragma unroll
    for (int c = 0; c < 8; c++) acc[c] = 0.f;
    double accd[8];
#pragma unroll
    for (int c = 0; c < 8; c++) accd[c] = 0.0;
    for (int r = blockIdx.x * 32 + r0; r < n; r += rowsPerGrid) {
        float v[8];
        load8h(X3 + (size_t)r * D + c8 * 8, v);
        const float4* xp = (const float4*)(x0 + (size_t)r * D + c8 * 8);
        float4 x0a = xp[0], x0b = xp[1];
        float xr[8] = {x0a.x, x0a.y, x0a.z, x0a.w, x0b.x, x0b.y, x0b.z, x0b.w};
#pragma unroll
        for (int c = 0; c < 8; c++) {
            float t = fmaf(v[c], sc[c], sh[c]);
            accd[c] += (double)(xr[c] + gelu_f(t));
        }
    }
    __shared__ double shm[256][8];
#pragma unroll
    for (int c = 0; c < 8; c++) shm[threadIdx.x][c] = accd[c];
    __syncthreads();
    // reduce the 32 row-groups for each channel-octet
    if (threadIdx.x < 8) {
        int cg = threadIdx.x;   // channel octet == c8 group
#pragma unroll
        for (int c = 0; c < 8; c++) {
            double t = 0.0;
            for (int rr = 0; rr < 32; rr++) t += shm[rr * 8 + cg][c];
            atomicAdd(&pool[cg * 8 + c], t);
        }
    }
}

// ---- head MLP: 64 ->128 ->64 ->32 ->1, single block ----
__global__ __launch_bounds__(128) void mlp_kernel(const double* __restrict__ pool,
                                                  const float* __restrict__ w1, const float* __restrict__ b1,
                                                  const float* __restrict__ w2, const float* __restrict__ b2,
                                                  const float* __restrict__ w3, const float* __restrict__ b3,
                                                  const float* __restrict__ w4, const float* __restrict__ b4,
                                                  float* __restrict__ out, int n) {
    __shared__ float v0[64], h1[128], h2[64], h3[32];
    int t = threadIdx.x;
    if (t < 64) v0[t] = (float)(pool[t] / (double)n);
    __syncthreads();
    if (t < 128) {
        float a = b1[t];
        for (int k = 0; k < 64; k++) a = fmaf(v0[k], w1[k * 128 + t], a);
        h1[t] = gelu_f(a);
    }
    __syncthreads();
    if (t < 64) {
        float a = b2[t];
        for (int k = 0; k < 128; k++) a = fmaf(h1[k], w2[k * 64 + t], a);
        h2[t] = gelu_f(a);
    }
    __syncthreads();
    if (t < 32) {
        float a = b3[t];
        for (int k = 0; k < 64; k++) a = fmaf(h2[k], w3[k * 32 + t], a);
        h3[t] = gelu_f(a);
    }
    __syncthreads();
    if (t == 0) {
        float a = b4[0];
        for (int k = 0; k < 32; k++) a = fmaf(h3[k], w4[k], a);
        out[0] = a;
    }
}

extern "C" void kernel_launch(void* const* d_in, const int* in_sizes, int n_in,
                              void* d_out, int out_size, void* d_ws, size_t ws_size,
                              hipStream_t stream) {
    const float* x    = (const float*)d_in[0];
    const int*   ei   = (const int*)d_in[1];
    const float* W1   = (const float*)d_in[2];
    const float* b1   = (const float*)d_in[3];
    const float* g1   = (const float*)d_in[4];
    const float* be1  = (const float*)d_in[5];
    const float* W2   = (const float*)d_in[6];
    const float* b2   = (const float*)d_in[7];
    const float* g2   = (const float*)d_in[8];
    const float* be2  = (const float*)d_in[9];
    const float* W3   = (const float*)d_in[10];
    const float* b3   = (const float*)d_in[11];
    const float* g3   = (const float*)d_in[12];
    const float* be3  = (const float*)d_in[13];
    const float* fc1w = (const float*)d_in[14];
    const float* fc1b = (const float*)d_in[15];
    const float* fc2w = (const float*)d_in[16];
    const float* fc2b = (const float*)d_in[17];
    const float* fc3w = (const float*)d_in[18];
    const float* fc3b = (const float*)d_in[19];
    const float* fc4w = (const float*)d_in[20];
    const float* fc4b = (const float*)d_in[21];

    const int N = in_sizes[0] / 64;
    const int E = in_sizes[1] / 2;
    const int* e_row = ei;       // source
    const int* e_col = ei + E;   // target (aggregation index)
    const int nbuckets = (N + 255) >> 8;

    // ---- workspace layout ----
    char* ws = (char*)d_ws;
    size_t off = 0;
    double* pool   = (double*)(ws + off); off += 64 * sizeof(double);
    double* tmp1   = (double*)(ws + off); off += 64 * 256 * sizeof(double);
    double* tmp2   = (double*)(ws + off); off += 64 * 256 * sizeof(double);
    double* tmp3   = (double*)(ws + off); off += 64 * 128 * sizeof(double);
    double* stats3 = (double*)(ws + off); off += 128 * sizeof(double);
    const int NDBL = 64 + 64 * 256 * 2 + 64 * 128 + 128;
    float* scale1 = (float*)(ws + off); off += 128 * sizeof(float);
    float* shift1 = (float*)(ws + off); off += 128 * sizeof(float);
    float* scale2 = (float*)(ws + off); off += 128 * sizeof(float);
    float* shift2 = (float*)(ws + off); off += 128 * sizeof(float);
    _Float16* Wf1 = (_Float16*)(ws + off); off += 64 * 128 * sizeof(_Float16);
    _Float16* Wf2 = (_Float16*)(ws + off); off += 128 * 128 * sizeof(_Float16);
    _Float16* Wf3 = (_Float16*)(ws + off); off += 128 * 64 * sizeof(_Float16);
    float* deg   = (float*)(ws + off); off += (size_t)N * sizeof(float);
    float* dinv  = (float*)(ws + off); off += (size_t)N * sizeof(float);
    off = (off + 15) & ~(size_t)15;
    int* offs       = (int*)(ws + off); off += (size_t)N * sizeof(int);
    int* bucketCnt  = (int*)(ws + off); off += 512 * sizeof(int);
    int* bucketBase = (int*)(ws + off); off += 520 * sizeof(int);
    int* bcur       = (int*)(ws + off); off += 512 * sizeof(int);
    int* csr     = (int*)(ws + off); off += (size_t)E * sizeof(int);
    unsigned int* stage = (unsigned int*)(ws + off); off += (size_t)E * sizeof(unsigned int);
    off = (off + 255) & ~(size_t)255;
    __half* Ut   = (__half*)(ws + off); off += (size_t)N * 128 * sizeof(__half);  // fp16 gather table
    __half* A1   = (__half*)(ws + off); off += (size_t)N * 64 * sizeof(__half);   // agg1 out (fp16)
    __half* H    = (__half*)(ws + off); off += (size_t)N * 128 * sizeof(__half);  // fp16 features
    __half* xh   = Ut;  // alias: xh dead after agg1, before gemm2 writes Ut

    const int nb256 = (N + 255) / 256;
    const int eblk = (E + EPB - 1) / EPB;
    const int gblk = (N + 63) / 64;

    // CSR build: histogram -> scan -> stage -> finalize (deg/dinv/offs/csr)
    init_kernel<<<nb256, 256, 0, stream>>>(pool, NDBL, bucketCnt);
    coarse_count_kernel<<<eblk, 512, 0, stream>>>(e_col, bucketCnt, E, nbuckets);
    bucket_scan_kernel<<<1, 512, 0, stream>>>(bucketCnt, bucketBase, bcur, nbuckets, E);
    binstage_kernel<<<eblk, 512, 0, stream>>>(e_row, e_col, bcur, stage, E, nbuckets);
    bucket_finalize_kernel<<<nbuckets, 256, 0, stream>>>(stage, bucketBase, deg, dinv,
                                                         offs, csr, N);

    // W -> fragment-ordered fp16 (tiny, once)
    wconv_kernel<64, 128><<<32, 256, 0, stream>>>(W1, Wf1);
    wconv_kernel<128, 128><<<64, 256, 0, stream>>>(W2, Wf2);
    wconv_kernel<128, 64><<<32, 256, 0, stream>>>(W3, Wf3);

    // Layer 1: x -> fp16 (dinv-scaled); agg 64-dim -> A1 (fp16); MFMA GEMM -> H1 (fp16)
    halfconv_kernel<<<(N * 8 + 255) / 256, 256, 0, stream>>>(x, dinv, xh, N);
    agg_kernel<64, false, false><<<(N + 31) / 32, 256, 0, stream>>>(
        xh, csr, offs, deg, dinv, nullptr, A1, nullptr, N);
    mgemm_kernel<64, 128, false, true, false, true, true><<<gblk, 256, 0, stream>>>(
        A1, Wf1, nullptr, nullptr, b1, nullptr, H, tmp1, N);
    finalize_tmp_kernel<128><<<1, 128, 0, stream>>>(tmp1, g1, be1, scale1, shift1, N);

    // Layer 2: MFMA GEMM (BN1+GELU fused, dinv prescale) -> Ut; agg -> H2 (fp16)
    mgemm_kernel<128, 128, true, false, true, true, false><<<gblk, 256, 0, stream>>>(
        H, Wf2, scale1, shift1, nullptr, dinv, Ut, nullptr, N);
    agg_kernel<128, true, true><<<(N + 15) / 16, 256, 0, stream>>>(
        Ut, csr, offs, deg, dinv, b2, H, tmp2, N);
    finalize_tmp_kernel<128><<<1, 128, 0, stream>>>(tmp2, g2, be2, scale2, shift2, N);

    // Layer 3: MFMA GEMM (BN2+GELU fused, dinv prescale) 128->64 -> Ut; agg -> H3 (fp16)
    mgemm_kernel<128, 64, true, false, true, true, false><<<gblk, 256, 0, stream>>>(
        H, Wf3, scale2, shift2, nullptr, dinv, Ut, nullptr, N);
    agg_kernel<64, true, true><<<(N + 31) / 32, 256, 0, stream>>>(
        Ut, csr, offs, deg, dinv, b3, H, tmp3, N);
    combine_kernel<64><<<1, 128, 0, stream>>>(tmp3, stats3);

    // Epilogue: BN3+GELU+residual+meanpool (fp16 H3), then head MLP
    norm_pool_kernel<<<1024, 256, 0, stream>>>(H, x, stats3, g3, be3, pool, N);
    mlp_kernel<<<1, 128, 0, stream>>>(pool, fc1w, fc1b, fc2w, fc2b, fc3w, fc3b,
                                      fc4w, fc4b, (float*)d_out, N);
}

// Round 17
// 309.070 us; speedup vs baseline: 1.4837x; 1.4837x over previous
//
#include <hip/hip_runtime.h>
#include <hip/hip_bf16.h>
#include <hip/hip_fp16.h>
#include <math.h>

// GNN: 3-layer GCN + BN + GELU + residual + meanpool + MLP -> scalar.
// R17: R16's fp16-H pipeline, with norm_pool REVERTED to the R15 structure
// (R16's rewrite was a 184us regression: 17% occupancy from 16KB double-LDS
// + serial 8-thread reduce; violation of one-variable-per-round). Only the
// X3 load is fp16 now. Everything else identical to R16.

typedef _Float16 f16x8 __attribute__((ext_vector_type(8)));
typedef _Float16 f16x4 __attribute__((ext_vector_type(4)));
typedef float f32x4 __attribute__((ext_vector_type(4)));

__device__ __forceinline__ float gelu_f(float x) {
    return 0.5f * x * (1.0f + erff(x * 0.7071067811865476f));
}

__device__ __forceinline__ int wave_incl_scan(int v, int lane) {
#pragma unroll
    for (int off = 1; off < 64; off <<= 1) {
        int t = __shfl_up(v, (unsigned)off, 64);
        if (lane >= off) v += t;
    }
    return v;
}

__device__ __forceinline__ void load8h(const __half* __restrict__ p, float* f) {
    uint4 u = *(const uint4*)p;
    const __half2* h2p = (const __half2*)&u;
#pragma unroll
    for (int i = 0; i < 4; i++) {
        float2 t = __half22float2(h2p[i]);
        f[2 * i] = t.x;
        f[2 * i + 1] = t.y;
    }
}

__device__ __forceinline__ void acc8h(const uint4& u, float* f) {
    const __half2* h2p = (const __half2*)&u;
#pragma unroll
    for (int i = 0; i < 4; i++) {
        float2 t = __half22float2(h2p[i]);
        f[2 * i] += t.x;
        f[2 * i + 1] += t.y;
    }
}

__device__ __forceinline__ uint4 pack8h(const float* f) {
    __half2 h[4];
#pragma unroll
    for (int i = 0; i < 4; i++) h[i] = __floats2half2_rn(f[2 * i], f[2 * i + 1]);
    return *(uint4*)h;
}

// ---- init: zero double accumulators + bucket counters ----
__global__ void init_kernel(double* __restrict__ dbls, int ndbl, int* __restrict__ bucketCnt) {
    int i = blockIdx.x * 256 + threadIdx.x;
    if (i < ndbl) dbls[i] = 0.0;
    if (i < 512) bucketCnt[i] = 0;
}

// ---- CSR step 1: coarse per-bucket edge counts (LDS histogram) ----
#define EPB 8192
__global__ __launch_bounds__(512) void coarse_count_kernel(const int* __restrict__ col,
                                                           int* __restrict__ bucketCnt,
                                                           int E, int nbuckets) {
    __shared__ int cnt[512];
    for (int b = threadIdx.x; b < nbuckets; b += 512) cnt[b] = 0;
    __syncthreads();
    int e0 = blockIdx.x * EPB;
    int eend = e0 + EPB;
    if (eend > E) eend = E;
    for (int e = e0 + threadIdx.x; e < eend; e += 512)
        atomicAdd(&cnt[col[e] >> 8], 1);
    __syncthreads();
    for (int b = threadIdx.x; b < nbuckets; b += 512) {
        int c = cnt[b];
        if (c) atomicAdd(&bucketCnt[b], c);
    }
}

// ---- CSR step 2: exclusive scan of bucket counts -> bases; init bcur ----
__global__ __launch_bounds__(512) void bucket_scan_kernel(const int* __restrict__ bucketCnt,
                                                          int* __restrict__ bucketBase,
                                                          int* __restrict__ bcur,
                                                          int nbuckets, int E) {
    int lane = threadIdx.x & 63;
    int wid = threadIdx.x >> 6;
    int v = (threadIdx.x < nbuckets) ? bucketCnt[threadIdx.x] : 0;
    int incl = wave_incl_scan(v, lane);
    __shared__ int ws[8];
    if (lane == 63) ws[wid] = incl;
    __syncthreads();
    if (threadIdx.x == 0) {
        int a = 0;
#pragma unroll
        for (int j = 0; j < 8; j++) { int t = ws[j]; ws[j] = a; a += t; }
    }
    __syncthreads();
    int excl = incl - v + ws[wid];
    if (threadIdx.x < nbuckets) {
        bucketBase[threadIdx.x] = excl;
        bcur[threadIdx.x] = excl;
    }
    if (threadIdx.x == 0) bucketBase[nbuckets] = E;
}

// ---- CSR step 3: LDS-binned stage. One global atomic per (block,bucket). ----
__global__ __launch_bounds__(512) void binstage_kernel(const int* __restrict__ row,
                                                       const int* __restrict__ col,
                                                       int* __restrict__ bcur,
                                                       unsigned int* __restrict__ stage,
                                                       int E, int nbuckets) {
    __shared__ int cnt[512];
    __shared__ int gbase[512];
    int e0 = blockIdx.x * EPB;
    int eend = e0 + EPB;
    if (eend > E) eend = E;
    for (int b = threadIdx.x; b < nbuckets; b += 512) cnt[b] = 0;
    __syncthreads();
    for (int e = e0 + threadIdx.x; e < eend; e += 512)
        atomicAdd(&cnt[col[e] >> 8], 1);
    __syncthreads();
    for (int b = threadIdx.x; b < nbuckets; b += 512) {
        int c = cnt[b];
        gbase[b] = c ? atomicAdd(&bcur[b], c) : 0;
        cnt[b] = 0;  // reuse as local cursor
    }
    __syncthreads();
    for (int e = e0 + threadIdx.x; e < eend; e += 512) {
        int c = col[e];
        int b = c >> 8;
        int lp = atomicAdd(&cnt[b], 1);
        stage[gbase[b] + lp] = ((unsigned int)row[e] << 8) | (unsigned int)(c & 255);
    }
}

// ---- CSR step 4: per-bucket degrees (coalesced deg/dinv/offs) + csr fill ----
__global__ __launch_bounds__(256) void bucket_finalize_kernel(const unsigned int* __restrict__ stage,
                                                              const int* __restrict__ bucketBase,
                                                              float* __restrict__ deg,
                                                              float* __restrict__ dinv,
                                                              int* __restrict__ offs,
                                                              int* __restrict__ csr,
                                                              int N) {
    __shared__ int cnt[256];
    __shared__ int loc[256];
    __shared__ int ws[4];
    int b = blockIdx.x;
    int nb0 = b << 8;
    int base = bucketBase[b];
    int end = bucketBase[b + 1];
    cnt[threadIdx.x] = 0;
    __syncthreads();
    int m = end - base;
    for (int t = threadIdx.x; t < m; t += 256)
        atomicAdd(&cnt[stage[base + t] & 255], 1);
    __syncthreads();
    int c = cnt[threadIdx.x];
    int lane = threadIdx.x & 63;
    int wid = threadIdx.x >> 6;
    int incl = wave_incl_scan(c, lane);
    if (lane == 63) ws[wid] = incl;
    __syncthreads();
    if (threadIdx.x == 0) {
        int a = 0;
#pragma unroll
        for (int j = 0; j < 4; j++) { int t = ws[j]; ws[j] = a; a += t; }
    }
    __syncthreads();
    int excl = incl - c + ws[wid];
    int node = nb0 + threadIdx.x;
    if (node < N) {
        float d = (float)(c + 1);
        deg[node] = d;
        dinv[node] = 1.0f / sqrtf(d);
        offs[node] = base + excl;
    }
    loc[threadIdx.x] = excl;
    __syncthreads();
    for (int t = threadIdx.x; t < m; t += 256) {
        unsigned int v = stage[base + t];
        int lc = v & 255;
        int src = (int)(v >> 8);
        int pos = atomicAdd(&loc[lc], 1);
        csr[base + pos] = src;
    }
}

// ---- convert x[N][64] fp32 -> xh[N][64] fp16, scaled by dinv[node] ----
__global__ __launch_bounds__(256) void halfconv_kernel(const float* __restrict__ x,
                                                       const float* __restrict__ dinv,
                                                       __half* __restrict__ xh, int N) {
    int t = blockIdx.x * 256 + threadIdx.x;   // one 8-float chunk per thread
    if (t >= N * 8) return;
    int node = t >> 3;
    float dv = dinv[node];
    const float4* p = (const float4*)(x + (size_t)t * 8);
    float4 a = p[0], b = p[1];
    __half2 h[4];
    h[0] = __floats2half2_rn(a.x * dv, a.y * dv);
    h[1] = __floats2half2_rn(a.z * dv, a.w * dv);
    h[2] = __floats2half2_rn(b.x * dv, b.y * dv);
    h[3] = __floats2half2_rn(b.z * dv, b.w * dv);
    *(uint4*)(xh + (size_t)t * 8) = *(uint4*)h;
}

// ---- convert W[DIN][DOUT] fp32 -> fragment-ordered fp16 Wf ----
template <int DIN, int DOUT>
__global__ void wconv_kernel(const float* __restrict__ W, _Float16* __restrict__ Wf) {
    int i = blockIdx.x * 256 + threadIdx.x;
    if (i >= DIN * DOUT) return;
    int k = i / DOUT, col = i - k * DOUT;
    int s = k >> 5, krem = k & 31;
    int lg = krem >> 3, j = krem & 7;
    int t = col >> 4, c = col & 15;
    constexpr int NT = DOUT / 16;
    int l = lg * 16 + c;
    Wf[((size_t)(s * NT + t) * 64 + l) * 8 + j] = (_Float16)W[(size_t)k * DOUT + col];
}

// ---- aggregation: H[i][D] = dinv_i*(Ut[i] + sum in-edge Ut[src]) (+bias) ----
// fp16 in, fp32 accumulate, fp16 out; stats from pre-rounding fp32.
template <int D, bool STATS, bool BIAS>
__global__ __launch_bounds__(256) void agg_kernel(const __half* __restrict__ Ut,
                                                  const int* __restrict__ csr,
                                                  const int* __restrict__ offs,
                                                  const float* __restrict__ deg,
                                                  const float* __restrict__ dinv,
                                                  const float* __restrict__ bias,
                                                  __half* __restrict__ H,
                                                  double* __restrict__ tmp, int n) {
    constexpr int GPN = D / 8;
    constexpr int NPB = 256 / GPN;
    int g = threadIdx.x / GPN;
    int cl = threadIdx.x % GPN;
    int node = blockIdx.x * NPB + g;
    bool act = node < n;

    float a[8], b[8];
#pragma unroll
    for (int c = 0; c < 8; c++) { a[c] = 0.f; b[c] = 0.f; }

    int start = 0, cnt = 0;
    float dvi = 0.f;
    if (act) {
        start = offs[node];
        cnt = (int)deg[node] - 1;
        dvi = dinv[node];
        load8h(Ut + (size_t)node * D + cl * 8, a);   // self loop (pre-scaled)
    }
    const __half* __restrict__ base = Ut + cl * 8;
    int j = 0;
    for (; j + 4 <= cnt; j += 4) {
        int s0 = csr[start + j];
        int s1 = csr[start + j + 1];
        int s2 = csr[start + j + 2];
        int s3 = csr[start + j + 3];
        uint4 u0 = *(const uint4*)(base + (size_t)s0 * D);
        uint4 u1 = *(const uint4*)(base + (size_t)s1 * D);
        uint4 u2 = *(const uint4*)(base + (size_t)s2 * D);
        uint4 u3 = *(const uint4*)(base + (size_t)s3 * D);
        acc8h(u0, a);
        acc8h(u1, b);
        acc8h(u2, a);
        acc8h(u3, b);
    }
    if (j + 2 <= cnt) {
        int s0 = csr[start + j];
        int s1 = csr[start + j + 1];
        uint4 u0 = *(const uint4*)(base + (size_t)s0 * D);
        uint4 u1 = *(const uint4*)(base + (size_t)s1 * D);
        acc8h(u0, a);
        acc8h(u1, b);
        j += 2;
    }
    if (j < cnt) {
        int s0 = csr[start + j];
        uint4 u0 = *(const uint4*)(base + (size_t)s0 * D);
        acc8h(u0, a);
    }

    float h[8];
#pragma unroll
    for (int c = 0; c < 8; c++) h[c] = (a[c] + b[c]) * dvi;
    if (BIAS) {
#pragma unroll
        for (int c = 0; c < 8; c++) h[c] += bias[cl * 8 + c];
    }
    if (act) {
        *(uint4*)(H + (size_t)node * D + cl * 8) = pack8h(h);
    } else {
#pragma unroll
        for (int c = 0; c < 8; c++) h[c] = 0.f;   // no stats contribution
    }

    if constexpr (STATS) {
        float s[8], q[8];
#pragma unroll
        for (int c = 0; c < 8; c++) { s[c] = h[c]; q[c] = h[c] * h[c]; }
#pragma unroll
        for (int m = GPN; m < 64; m <<= 1) {
#pragma unroll
            for (int c = 0; c < 8; c++) {
                s[c] += __shfl_xor(s[c], m, 64);
                q[c] += __shfl_xor(q[c], m, 64);
            }
        }
        __shared__ float ps[4][GPN][8], pq[4][GPN][8];
        int wid = threadIdx.x >> 6;
        int lane = threadIdx.x & 63;
        if (lane < GPN) {
#pragma unroll
            for (int c = 0; c < 8; c++) { ps[wid][lane][c] = s[c]; pq[wid][lane][c] = q[c]; }
        }
        __syncthreads();
        if (threadIdx.x < D) {
            int cgi = threadIdx.x >> 3, ci = threadIdx.x & 7;
            float t1 = ps[0][cgi][ci] + ps[1][cgi][ci] + ps[2][cgi][ci] + ps[3][cgi][ci];
            float t2 = pq[0][cgi][ci] + pq[1][cgi][ci] + pq[2][cgi][ci] + pq[3][cgi][ci];
            int cp = (blockIdx.x & 63) * 2 * D;
            atomicAdd(&tmp[cp + threadIdx.x], (double)t1);
            atomicAdd(&tmp[cp + D + threadIdx.x], (double)t2);
        }
    }
}

// ---- MFMA GEMM: Out[n][DOUT] = f(Hin)[n][DIN] @ W (+bias)(*dinv) ----
template <int DIN, int DOUT, bool BNIN, bool BIAS, bool DINVOUT, bool HALFOUT, bool STATS>
__global__ __launch_bounds__(256) void mgemm_kernel(const __half* __restrict__ Hin,
                                                    const _Float16* __restrict__ Wf,
                                                    const float* __restrict__ scale,
                                                    const float* __restrict__ shift,
                                                    const float* __restrict__ bias,
                                                    const float* __restrict__ dinv,
                                                    void* __restrict__ Out,
                                                    double* __restrict__ tmp, int n) {
    constexpr int NT = DOUT / 16;   // n-tiles per wave
    constexpr int NS = DIN / 32;    // k-steps
    constexpr int DP = DIN + 8;     // padded LDS row (halfs), keeps 16B align
    __shared__ _Float16 Hs[64 * DP];

    int node0 = blockIdx.x * 64;
    int nv = n - node0;
    if (nv > 64) nv = 64;

    constexpr int C8R = DIN / 8;
    for (int f = threadIdx.x; f < 64 * C8R; f += 256) {
        int nn = f / C8R, k8 = f - nn * C8R;
        float v[8];
        if (nn < nv) {
            load8h(Hin + (size_t)(node0 + nn) * DIN + k8 * 8, v);
        } else {
#pragma unroll
            for (int c = 0; c < 8; c++) v[c] = 0.f;
        }
        if (BNIN && nn < nv) {
            float4 sc0 = *(const float4*)(scale + k8 * 8);
            float4 sc1 = *(const float4*)(scale + k8 * 8 + 4);
            float4 sh0 = *(const float4*)(shift + k8 * 8);
            float4 sh1 = *(const float4*)(shift + k8 * 8 + 4);
            v[0] = gelu_f(fmaf(v[0], sc0.x, sh0.x));
            v[1] = gelu_f(fmaf(v[1], sc0.y, sh0.y));
            v[2] = gelu_f(fmaf(v[2], sc0.z, sh0.z));
            v[3] = gelu_f(fmaf(v[3], sc0.w, sh0.w));
            v[4] = gelu_f(fmaf(v[4], sc1.x, sh1.x));
            v[5] = gelu_f(fmaf(v[5], sc1.y, sh1.y));
            v[6] = gelu_f(fmaf(v[6], sc1.z, sh1.z));
            v[7] = gelu_f(fmaf(v[7], sc1.w, sh1.w));
        }
        f16x8 h;
#pragma unroll
        for (int c = 0; c < 8; c++) h[c] = (_Float16)v[c];
        *(f16x8*)(&Hs[nn * DP + k8 * 8]) = h;
    }
    __syncthreads();

    int wv = threadIdx.x >> 6;
    int l = threadIdx.x & 63;
    int arow = l & 15, agrp = l >> 4;

    f32x4 acc[NT];
#pragma unroll
    for (int t = 0; t < NT; t++) acc[t] = (f32x4){0.f, 0.f, 0.f, 0.f};

    const _Float16* hrow = &Hs[(wv * 16 + arow) * DP];
#pragma unroll
    for (int s = 0; s < NS; s++) {
        f16x8 a = *(const f16x8*)(hrow + s * 32 + agrp * 8);
        const _Float16* wb = Wf + (size_t)s * NT * 512 + l * 8;
#pragma unroll
        for (int t = 0; t < NT; t++) {
            f16x8 b = *(const f16x8*)(wb + (size_t)t * 512);
            acc[t] = __builtin_amdgcn_mfma_f32_16x16x32_f16(a, b, acc[t], 0, 0, 0);
        }
    }

    int rbase = wv * 16 + agrp * 4;
    float dv4[4] = {1.f, 1.f, 1.f, 1.f};
    if (DINVOUT) {
#pragma unroll
        for (int r = 0; r < 4; r++)
            if (rbase + r < nv) dv4[r] = dinv[node0 + rbase + r];
    }
    float sa[NT], qa[NT];
#pragma unroll
    for (int t = 0; t < NT; t++) {
        int col = t * 16 + arow;
        float bcol = BIAS ? bias[col] : 0.f;
        float ssum = 0.f, qsum = 0.f;
#pragma unroll
        for (int r = 0; r < 4; r++) {
            int nn = rbase + r;
            bool valid = nn < nv;
            float v = acc[t][r];
            if (DINVOUT) v *= dv4[r];
            v += bcol;
            v = valid ? v : 0.f;
            if (valid) {
                size_t oi = (size_t)(node0 + nn) * DOUT + col;
                ((__half*)Out)[oi] = __float2half(v);
            }
            ssum += v;
            qsum += v * v;
        }
        sa[t] = ssum;
        qa[t] = qsum;
    }

    if constexpr (STATS) {
        __shared__ float ps[4][DOUT], pq[4][DOUT];
#pragma unroll
        for (int t = 0; t < NT; t++) {
            float s = sa[t], q = qa[t];
            s += __shfl_xor(s, 16, 64); q += __shfl_xor(q, 16, 64);
            s += __shfl_xor(s, 32, 64); q += __shfl_xor(q, 32, 64);
            if (l < 16) { ps[wv][t * 16 + l] = s; pq[wv][t * 16 + l] = q; }
        }
        __syncthreads();
        if (threadIdx.x < DOUT) {
            float t1 = ps[0][threadIdx.x] + ps[1][threadIdx.x] +
                       ps[2][threadIdx.x] + ps[3][threadIdx.x];
            float t2 = pq[0][threadIdx.x] + pq[1][threadIdx.x] +
                       pq[2][threadIdx.x] + pq[3][threadIdx.x];
            int cp = (blockIdx.x & 63) * 2 * DOUT;
            atomicAdd(&tmp[cp + threadIdx.x], (double)t1);
            atomicAdd(&tmp[cp + DOUT + threadIdx.x], (double)t2);
        }
    }
}

// ---- fold 64 tmp copies -> per-channel scale/shift floats ----
template <int D>
__global__ void finalize_tmp_kernel(const double* __restrict__ tmp,
                                    const float* __restrict__ g, const float* __restrict__ be,
                                    float* __restrict__ scale, float* __restrict__ shift, int n) {
    int c = threadIdx.x;
    if (c < D) {
        double s = 0.0, q = 0.0;
        for (int gg = 0; gg < 64; gg++) {
            s += tmp[gg * 2 * D + c];
            q += tmp[gg * 2 * D + D + c];
        }
        double mu = s / n;
        double var = q / n - mu * mu;
        double inv = 1.0 / sqrt(var + 1e-5);
        double sc = (double)g[c] * inv;
        scale[c] = (float)sc;
        shift[c] = (float)((double)be[c] - mu * sc);
    }
}

// ---- fold 64 tmp copies -> raw stats sums (for norm_pool) ----
template <int D>
__global__ void combine_kernel(const double* __restrict__ tmp, double* __restrict__ stats) {
    int t = threadIdx.x;
    if (t < 2 * D) {
        double s = 0.0;
        for (int gg = 0; gg < 64; gg++) s += tmp[gg * 2 * D + t];
        stats[t] = s;
    }
}

// ---- layer-3: BN normalize + GELU + residual(x) + mean-pool (R15 structure) ----
__global__ __launch_bounds__(256) void norm_pool_kernel(const __half* __restrict__ X3,
                                                        const float* __restrict__ x0,
                                                        const double* __restrict__ stats,
                                                        const float* __restrict__ gw,
                                                        const float* __restrict__ be,
                                                        double* __restrict__ pool, int n) {
    constexpr int D = 64;
    constexpr int RPB = 4;
    int c = threadIdx.x % D;
    double mu = stats[c] / n;
    double var = stats[c + D] / n - mu * mu;
    double inv = 1.0 / sqrt(var + 1e-5);
    float scale = (float)((double)gw[c] * inv);
    float shift = (float)((double)be[c] - mu * (double)gw[c] * inv);
    int r0 = threadIdx.x / D;
    int rowsPerGrid = gridDim.x * RPB;
    double s = 0.0;
    for (int r = blockIdx.x * RPB + r0; r < n; r += rowsPerGrid) {
        size_t idx = (size_t)r * D + c;
        float t = fmaf(__half2float(X3[idx]), scale, shift);
        float res = x0[idx] + gelu_f(t);
        s += res;
    }
    __shared__ double sh[256];
    sh[threadIdx.x] = s;
    __syncthreads();
    if (threadIdx.x < D) {
#pragma unroll
        for (int j = 1; j < RPB; j++) s += sh[threadIdx.x + j * D];
        atomicAdd(&pool[c], s);
    }
}

// ---- head MLP: 64 ->128 ->64 ->32 ->1, single block ----
__global__ __launch_bounds__(128) void mlp_kernel(const double* __restrict__ pool,
                                                  const float* __restrict__ w1, const float* __restrict__ b1,
                                                  const float* __restrict__ w2, const float* __restrict__ b2,
                                                  const float* __restrict__ w3, const float* __restrict__ b3,
                                                  const float* __restrict__ w4, const float* __restrict__ b4,
                                                  float* __restrict__ out, int n) {
    __shared__ float v0[64], h1[128], h2[64], h3[32];
    int t = threadIdx.x;
    if (t < 64) v0[t] = (float)(pool[t] / (double)n);
    __syncthreads();
    if (t < 128) {
        float a = b1[t];
        for (int k = 0; k < 64; k++) a = fmaf(v0[k], w1[k * 128 + t], a);
        h1[t] = gelu_f(a);
    }
    __syncthreads();
    if (t < 64) {
        float a = b2[t];
        for (int k = 0; k < 128; k++) a = fmaf(h1[k], w2[k * 64 + t], a);
        h2[t] = gelu_f(a);
    }
    __syncthreads();
    if (t < 32) {
        float a = b3[t];
        for (int k = 0; k < 64; k++) a = fmaf(h2[k], w3[k * 32 + t], a);
        h3[t] = gelu_f(a);
    }
    __syncthreads();
    if (t == 0) {
        float a = b4[0];
        for (int k = 0; k < 32; k++) a = fmaf(h3[k], w4[k], a);
        out[0] = a;
    }
}

extern "C" void kernel_launch(void* const* d_in, const int* in_sizes, int n_in,
                              void* d_out, int out_size, void* d_ws, size_t ws_size,
                              hipStream_t stream) {
    const float* x    = (const float*)d_in[0];
    const int*   ei   = (const int*)d_in[1];
    const float* W1   = (const float*)d_in[2];
    const float* b1   = (const float*)d_in[3];
    const float* g1   = (const float*)d_in[4];
    const float* be1  = (const float*)d_in[5];
    const float* W2   = (const float*)d_in[6];
    const float* b2   = (const float*)d_in[7];
    const float* g2   = (const float*)d_in[8];
    const float* be2  = (const float*)d_in[9];
    const float* W3   = (const float*)d_in[10];
    const float* b3   = (const float*)d_in[11];
    const float* g3   = (const float*)d_in[12];
    const float* be3  = (const float*)d_in[13];
    const float* fc1w = (const float*)d_in[14];
    const float* fc1b = (const float*)d_in[15];
    const float* fc2w = (const float*)d_in[16];
    const float* fc2b = (const float*)d_in[17];
    const float* fc3w = (const float*)d_in[18];
    const float* fc3b = (const float*)d_in[19];
    const float* fc4w = (const float*)d_in[20];
    const float* fc4b = (const float*)d_in[21];

    const int N = in_sizes[0] / 64;
    const int E = in_sizes[1] / 2;
    const int* e_row = ei;       // source
    const int* e_col = ei + E;   // target (aggregation index)
    const int nbuckets = (N + 255) >> 8;

    // ---- workspace layout ----
    char* ws = (char*)d_ws;
    size_t off = 0;
    double* pool   = (double*)(ws + off); off += 64 * sizeof(double);
    double* tmp1   = (double*)(ws + off); off += 64 * 256 * sizeof(double);
    double* tmp2   = (double*)(ws + off); off += 64 * 256 * sizeof(double);
    double* tmp3   = (double*)(ws + off); off += 64 * 128 * sizeof(double);
    double* stats3 = (double*)(ws + off); off += 128 * sizeof(double);
    const int NDBL = 64 + 64 * 256 * 2 + 64 * 128 + 128;
    float* scale1 = (float*)(ws + off); off += 128 * sizeof(float);
    float* shift1 = (float*)(ws + off); off += 128 * sizeof(float);
    float* scale2 = (float*)(ws + off); off += 128 * sizeof(float);
    float* shift2 = (float*)(ws + off); off += 128 * sizeof(float);
    _Float16* Wf1 = (_Float16*)(ws + off); off += 64 * 128 * sizeof(_Float16);
    _Float16* Wf2 = (_Float16*)(ws + off); off += 128 * 128 * sizeof(_Float16);
    _Float16* Wf3 = (_Float16*)(ws + off); off += 128 * 64 * sizeof(_Float16);
    float* deg   = (float*)(ws + off); off += (size_t)N * sizeof(float);
    float* dinv  = (float*)(ws + off); off += (size_t)N * sizeof(float);
    off = (off + 15) & ~(size_t)15;
    int* offs       = (int*)(ws + off); off += (size_t)N * sizeof(int);
    int* bucketCnt  = (int*)(ws + off); off += 512 * sizeof(int);
    int* bucketBase = (int*)(ws + off); off += 520 * sizeof(int);
    int* bcur       = (int*)(ws + off); off += 512 * sizeof(int);
    int* csr     = (int*)(ws + off); off += (size_t)E * sizeof(int);
    unsigned int* stage = (unsigned int*)(ws + off); off += (size_t)E * sizeof(unsigned int);
    off = (off + 255) & ~(size_t)255;
    __half* Ut   = (__half*)(ws + off); off += (size_t)N * 128 * sizeof(__half);  // fp16 gather table
    __half* A1   = (__half*)(ws + off); off += (size_t)N * 64 * sizeof(__half);   // agg1 out (fp16)
    __half* H    = (__half*)(ws + off); off += (size_t)N * 128 * sizeof(__half);  // fp16 features
    __half* xh   = Ut;  // alias: xh dead after agg1, before gemm2 writes Ut

    const int nb256 = (N + 255) / 256;
    const int eblk = (E + EPB - 1) / EPB;
    const int gblk = (N + 63) / 64;

    // CSR build: histogram -> scan -> stage -> finalize (deg/dinv/offs/csr)
    init_kernel<<<nb256, 256, 0, stream>>>(pool, NDBL, bucketCnt);
    coarse_count_kernel<<<eblk, 512, 0, stream>>>(e_col, bucketCnt, E, nbuckets);
    bucket_scan_kernel<<<1, 512, 0, stream>>>(bucketCnt, bucketBase, bcur, nbuckets, E);
    binstage_kernel<<<eblk, 512, 0, stream>>>(e_row, e_col, bcur, stage, E, nbuckets);
    bucket_finalize_kernel<<<nbuckets, 256, 0, stream>>>(stage, bucketBase, deg, dinv,
                                                         offs, csr, N);

    // W -> fragment-ordered fp16 (tiny, once)
    wconv_kernel<64, 128><<<32, 256, 0, stream>>>(W1, Wf1);
    wconv_kernel<128, 128><<<64, 256, 0, stream>>>(W2, Wf2);
    wconv_kernel<128, 64><<<32, 256, 0, stream>>>(W3, Wf3);

    // Layer 1: x -> fp16 (dinv-scaled); agg 64-dim -> A1 (fp16); MFMA GEMM -> H1 (fp16)
    halfconv_kernel<<<(N * 8 + 255) / 256, 256, 0, stream>>>(x, dinv, xh, N);
    agg_kernel<64, false, false><<<(N + 31) / 32, 256, 0, stream>>>(
        xh, csr, offs, deg, dinv, nullptr, A1, nullptr, N);
    mgemm_kernel<64, 128, false, true, false, true, true><<<gblk, 256, 0, stream>>>(
        A1, Wf1, nullptr, nullptr, b1, nullptr, H, tmp1, N);
    finalize_tmp_kernel<128><<<1, 128, 0, stream>>>(tmp1, g1, be1, scale1, shift1, N);

    // Layer 2: MFMA GEMM (BN1+GELU fused, dinv prescale) -> Ut; agg -> H2 (fp16)
    mgemm_kernel<128, 128, true, false, true, true, false><<<gblk, 256, 0, stream>>>(
        H, Wf2, scale1, shift1, nullptr, dinv, Ut, nullptr, N);
    agg_kernel<128, true, true><<<(N + 15) / 16, 256, 0, stream>>>(
        Ut, csr, offs, deg, dinv, b2, H, tmp2, N);
    finalize_tmp_kernel<128><<<1, 128, 0, stream>>>(tmp2, g2, be2, scale2, shift2, N);

    // Layer 3: MFMA GEMM (BN2+GELU fused, dinv prescale) 128->64 -> Ut; agg -> H3 (fp16)
    mgemm_kernel<128, 64, true, false, true, true, false><<<gblk, 256, 0, stream>>>(
        H, Wf3, scale2, shift2, nullptr, dinv, Ut, nullptr, N);
    agg_kernel<64, true, true><<<(N + 31) / 32, 256, 0, stream>>>(
        Ut, csr, offs, deg, dinv, b3, H, tmp3, N);
    combine_kernel<64><<<1, 128, 0, stream>>>(tmp3, stats3);

    // Epilogue: BN3+GELU+residual+meanpool (fp16 H3), then head MLP
    norm_pool_kernel<<<1024, 256, 0, stream>>>(H, x, stats3, g3, be3, pool, N);
    mlp_kernel<<<1, 128, 0, stream>>>(pool, fc1w, fc1b, fc2w, fc2b, fc3w, fc3b,
                                      fc4w, fc4b, (float*)d_out, N);
}

// Round 18
// 307.032 us; speedup vs baseline: 1.4935x; 1.0066x over previous
//
#include <hip/hip_runtime.h>
#include <hip/hip_bf16.h>
#include <hip/hip_fp16.h>
#include <math.h>

// GNN: 3-layer GCN + BN + GELU + residual + meanpool + MLP -> scalar.
// R18: R17 (309us) + final polish: (1) residual pool split mean(x+h) =
// mean(x)+mean(h): x channel-sums computed in halfconv (already reads x),
// norm_pool drops its 25.6MB x0 read; (2) one wconv dispatch for all 3 Ws.
// agg / mgemm / CSR build / stats byte-identical to R17.

typedef _Float16 f16x8 __attribute__((ext_vector_type(8)));
typedef _Float16 f16x4 __attribute__((ext_vector_type(4)));
typedef float f32x4 __attribute__((ext_vector_type(4)));

__device__ __forceinline__ float gelu_f(float x) {
    return 0.5f * x * (1.0f + erff(x * 0.7071067811865476f));
}

__device__ __forceinline__ int wave_incl_scan(int v, int lane) {
#pragma unroll
    for (int off = 1; off < 64; off <<= 1) {
        int t = __shfl_up(v, (unsigned)off, 64);
        if (lane >= off) v += t;
    }
    return v;
}

__device__ __forceinline__ void load8h(const __half* __restrict__ p, float* f) {
    uint4 u = *(const uint4*)p;
    const __half2* h2p = (const __half2*)&u;
#pragma unroll
    for (int i = 0; i < 4; i++) {
        float2 t = __half22float2(h2p[i]);
        f[2 * i] = t.x;
        f[2 * i + 1] = t.y;
    }
}

__device__ __forceinline__ void acc8h(const uint4& u, float* f) {
    const __half2* h2p = (const __half2*)&u;
#pragma unroll
    for (int i = 0; i < 4; i++) {
        float2 t = __half22float2(h2p[i]);
        f[2 * i] += t.x;
        f[2 * i + 1] += t.y;
    }
}

__device__ __forceinline__ uint4 pack8h(const float* f) {
    __half2 h[4];
#pragma unroll
    for (int i = 0; i < 4; i++) h[i] = __floats2half2_rn(f[2 * i], f[2 * i + 1]);
    return *(uint4*)h;
}

// ---- init: zero double accumulators + bucket counters ----
__global__ void init_kernel(double* __restrict__ dbls, int ndbl, int* __restrict__ bucketCnt) {
    int i = blockIdx.x * 256 + threadIdx.x;
    if (i < ndbl) dbls[i] = 0.0;
    if (i < 512) bucketCnt[i] = 0;
}

// ---- CSR step 1: coarse per-bucket edge counts (LDS histogram) ----
#define EPB 8192
__global__ __launch_bounds__(512) void coarse_count_kernel(const int* __restrict__ col,
                                                           int* __restrict__ bucketCnt,
                                                           int E, int nbuckets) {
    __shared__ int cnt[512];
    for (int b = threadIdx.x; b < nbuckets; b += 512) cnt[b] = 0;
    __syncthreads();
    int e0 = blockIdx.x * EPB;
    int eend = e0 + EPB;
    if (eend > E) eend = E;
    for (int e = e0 + threadIdx.x; e < eend; e += 512)
        atomicAdd(&cnt[col[e] >> 8], 1);
    __syncthreads();
    for (int b = threadIdx.x; b < nbuckets; b += 512) {
        int c = cnt[b];
        if (c) atomicAdd(&bucketCnt[b], c);
    }
}

// ---- CSR step 2: exclusive scan of bucket counts -> bases; init bcur ----
__global__ __launch_bounds__(512) void bucket_scan_kernel(const int* __restrict__ bucketCnt,
                                                          int* __restrict__ bucketBase,
                                                          int* __restrict__ bcur,
                                                          int nbuckets, int E) {
    int lane = threadIdx.x & 63;
    int wid = threadIdx.x >> 6;
    int v = (threadIdx.x < nbuckets) ? bucketCnt[threadIdx.x] : 0;
    int incl = wave_incl_scan(v, lane);
    __shared__ int ws[8];
    if (lane == 63) ws[wid] = incl;
    __syncthreads();
    if (threadIdx.x == 0) {
        int a = 0;
#pragma unroll
        for (int j = 0; j < 8; j++) { int t = ws[j]; ws[j] = a; a += t; }
    }
    __syncthreads();
    int excl = incl - v + ws[wid];
    if (threadIdx.x < nbuckets) {
        bucketBase[threadIdx.x] = excl;
        bcur[threadIdx.x] = excl;
    }
    if (threadIdx.x == 0) bucketBase[nbuckets] = E;
}

// ---- CSR step 3: LDS-binned stage. One global atomic per (block,bucket). ----
__global__ __launch_bounds__(512) void binstage_kernel(const int* __restrict__ row,
                                                       const int* __restrict__ col,
                                                       int* __restrict__ bcur,
                                                       unsigned int* __restrict__ stage,
                                                       int E, int nbuckets) {
    __shared__ int cnt[512];
    __shared__ int gbase[512];
    int e0 = blockIdx.x * EPB;
    int eend = e0 + EPB;
    if (eend > E) eend = E;
    for (int b = threadIdx.x; b < nbuckets; b += 512) cnt[b] = 0;
    __syncthreads();
    for (int e = e0 + threadIdx.x; e < eend; e += 512)
        atomicAdd(&cnt[col[e] >> 8], 1);
    __syncthreads();
    for (int b = threadIdx.x; b < nbuckets; b += 512) {
        int c = cnt[b];
        gbase[b] = c ? atomicAdd(&bcur[b], c) : 0;
        cnt[b] = 0;  // reuse as local cursor
    }
    __syncthreads();
    for (int e = e0 + threadIdx.x; e < eend; e += 512) {
        int c = col[e];
        int b = c >> 8;
        int lp = atomicAdd(&cnt[b], 1);
        stage[gbase[b] + lp] = ((unsigned int)row[e] << 8) | (unsigned int)(c & 255);
    }
}

// ---- CSR step 4: per-bucket degrees (coalesced deg/dinv/offs) + csr fill ----
__global__ __launch_bounds__(256) void bucket_finalize_kernel(const unsigned int* __restrict__ stage,
                                                              const int* __restrict__ bucketBase,
                                                              float* __restrict__ deg,
                                                              float* __restrict__ dinv,
                                                              int* __restrict__ offs,
                                                              int* __restrict__ csr,
                                                              int N) {
    __shared__ int cnt[256];
    __shared__ int loc[256];
    __shared__ int ws[4];
    int b = blockIdx.x;
    int nb0 = b << 8;
    int base = bucketBase[b];
    int end = bucketBase[b + 1];
    cnt[threadIdx.x] = 0;
    __syncthreads();
    int m = end - base;
    for (int t = threadIdx.x; t < m; t += 256)
        atomicAdd(&cnt[stage[base + t] & 255], 1);
    __syncthreads();
    int c = cnt[threadIdx.x];
    int lane = threadIdx.x & 63;
    int wid = threadIdx.x >> 6;
    int incl = wave_incl_scan(c, lane);
    if (lane == 63) ws[wid] = incl;
    __syncthreads();
    if (threadIdx.x == 0) {
        int a = 0;
#pragma unroll
        for (int j = 0; j < 4; j++) { int t = ws[j]; ws[j] = a; a += t; }
    }
    __syncthreads();
    int excl = incl - c + ws[wid];
    int node = nb0 + threadIdx.x;
    if (node < N) {
        float d = (float)(c + 1);
        deg[node] = d;
        dinv[node] = 1.0f / sqrtf(d);
        offs[node] = base + excl;
    }
    loc[threadIdx.x] = excl;
    __syncthreads();
    for (int t = threadIdx.x; t < m; t += 256) {
        unsigned int v = stage[base + t];
        int lc = v & 255;
        int src = (int)(v >> 8);
        int pos = atomicAdd(&loc[lc], 1);
        csr[base + pos] = src;
    }
}

// ---- convert x[N][64] fp32 -> xh fp16 (dinv-scaled) + per-channel x sums ----
__global__ __launch_bounds__(256) void halfconv_kernel(const float* __restrict__ x,
                                                       const float* __restrict__ dinv,
                                                       __half* __restrict__ xh,
                                                       double* __restrict__ tmpx, int N) {
    int t = blockIdx.x * 256 + threadIdx.x;   // one 8-float chunk per thread
    int c8 = threadIdx.x & 7;
    float vs[8];
#pragma unroll
    for (int i = 0; i < 8; i++) vs[i] = 0.f;
    if (t < N * 8) {
        int node = t >> 3;
        float dv = dinv[node];
        const float4* p = (const float4*)(x + (size_t)t * 8);
        float4 a = p[0], b = p[1];
        vs[0] = a.x; vs[1] = a.y; vs[2] = a.z; vs[3] = a.w;
        vs[4] = b.x; vs[5] = b.y; vs[6] = b.z; vs[7] = b.w;
        __half2 h[4];
        h[0] = __floats2half2_rn(a.x * dv, a.y * dv);
        h[1] = __floats2half2_rn(a.z * dv, a.w * dv);
        h[2] = __floats2half2_rn(b.x * dv, b.y * dv);
        h[3] = __floats2half2_rn(b.z * dv, b.w * dv);
        *(uint4*)(xh + (size_t)t * 8) = *(uint4*)h;
    }
    // per-block channel sums of raw x (residual's pool contribution)
    __shared__ float lsum[256][8];
#pragma unroll
    for (int i = 0; i < 8; i++) lsum[threadIdx.x][i] = vs[i];
    __syncthreads();
    if (threadIdx.x < 64) {
        int cg = threadIdx.x >> 3;      // which c8 group
        int ci = threadIdx.x & 7;       // channel within group
        float s = 0.f;
#pragma unroll
        for (int rr = 0; rr < 32; rr++) s += lsum[rr * 8 + cg][ci];
        atomicAdd(&tmpx[(blockIdx.x & 63) * 64 + cg * 8 + ci], (double)s);
    }
}

// ---- convert all three W's -> fragment-ordered fp16 (one dispatch) ----
__device__ __forceinline__ void wfrag_store(const float* __restrict__ W,
                                            _Float16* __restrict__ Wf,
                                            int i, int DOUT) {
    int k = i / DOUT, col = i - k * DOUT;
    int s = k >> 5, krem = k & 31;
    int lg = krem >> 3, j = krem & 7;
    int t = col >> 4, c = col & 15;
    int NT = DOUT >> 4;
    int l = lg * 16 + c;
    Wf[((size_t)(s * NT + t) * 64 + l) * 8 + j] = (_Float16)W[(size_t)k * DOUT + col];
}

__global__ void wconv_all_kernel(const float* __restrict__ W1, _Float16* __restrict__ Wf1,
                                 const float* __restrict__ W2, _Float16* __restrict__ Wf2,
                                 const float* __restrict__ W3, _Float16* __restrict__ Wf3) {
    int i = blockIdx.x * 256 + threadIdx.x;
    if (i < 8192) {
        wfrag_store(W1, Wf1, i, 128);                    // 64x128
    } else if (i < 8192 + 16384) {
        wfrag_store(W2, Wf2, i - 8192, 128);             // 128x128
    } else if (i < 8192 + 16384 + 8192) {
        wfrag_store(W3, Wf3, i - 8192 - 16384, 64);      // 128x64
    }
}

// ---- aggregation: H[i][D] = dinv_i*(Ut[i] + sum in-edge Ut[src]) (+bias) ----
// fp16 in, fp32 accumulate, fp16 out; stats from pre-rounding fp32.
template <int D, bool STATS, bool BIAS>
__global__ __launch_bounds__(256) void agg_kernel(const __half* __restrict__ Ut,
                                                  const int* __restrict__ csr,
                                                  const int* __restrict__ offs,
                                                  const float* __restrict__ deg,
                                                  const float* __restrict__ dinv,
                                                  const float* __restrict__ bias,
                                                  __half* __restrict__ H,
                                                  double* __restrict__ tmp, int n) {
    constexpr int GPN = D / 8;
    constexpr int NPB = 256 / GPN;
    int g = threadIdx.x / GPN;
    int cl = threadIdx.x % GPN;
    int node = blockIdx.x * NPB + g;
    bool act = node < n;

    float a[8], b[8];
#pragma unroll
    for (int c = 0; c < 8; c++) { a[c] = 0.f; b[c] = 0.f; }

    int start = 0, cnt = 0;
    float dvi = 0.f;
    if (act) {
        start = offs[node];
        cnt = (int)deg[node] - 1;
        dvi = dinv[node];
        load8h(Ut + (size_t)node * D + cl * 8, a);   // self loop (pre-scaled)
    }
    const __half* __restrict__ base = Ut + cl * 8;
    int j = 0;
    for (; j + 4 <= cnt; j += 4) {
        int s0 = csr[start + j];
        int s1 = csr[start + j + 1];
        int s2 = csr[start + j + 2];
        int s3 = csr[start + j + 3];
        uint4 u0 = *(const uint4*)(base + (size_t)s0 * D);
        uint4 u1 = *(const uint4*)(base + (size_t)s1 * D);
        uint4 u2 = *(const uint4*)(base + (size_t)s2 * D);
        uint4 u3 = *(const uint4*)(base + (size_t)s3 * D);
        acc8h(u0, a);
        acc8h(u1, b);
        acc8h(u2, a);
        acc8h(u3, b);
    }
    if (j + 2 <= cnt) {
        int s0 = csr[start + j];
        int s1 = csr[start + j + 1];
        uint4 u0 = *(const uint4*)(base + (size_t)s0 * D);
        uint4 u1 = *(const uint4*)(base + (size_t)s1 * D);
        acc8h(u0, a);
        acc8h(u1, b);
        j += 2;
    }
    if (j < cnt) {
        int s0 = csr[start + j];
        uint4 u0 = *(const uint4*)(base + (size_t)s0 * D);
        acc8h(u0, a);
    }

    float h[8];
#pragma unroll
    for (int c = 0; c < 8; c++) h[c] = (a[c] + b[c]) * dvi;
    if (BIAS) {
#pragma unroll
        for (int c = 0; c < 8; c++) h[c] += bias[cl * 8 + c];
    }
    if (act) {
        *(uint4*)(H + (size_t)node * D + cl * 8) = pack8h(h);
    } else {
#pragma unroll
        for (int c = 0; c < 8; c++) h[c] = 0.f;   // no stats contribution
    }

    if constexpr (STATS) {
        float s[8], q[8];
#pragma unroll
        for (int c = 0; c < 8; c++) { s[c] = h[c]; q[c] = h[c] * h[c]; }
#pragma unroll
        for (int m = GPN; m < 64; m <<= 1) {
#pragma unroll
            for (int c = 0; c < 8; c++) {
                s[c] += __shfl_xor(s[c], m, 64);
                q[c] += __shfl_xor(q[c], m, 64);
            }
        }
        __shared__ float ps[4][GPN][8], pq[4][GPN][8];
        int wid = threadIdx.x >> 6;
        int lane = threadIdx.x & 63;
        if (lane < GPN) {
#pragma unroll
            for (int c = 0; c < 8; c++) { ps[wid][lane][c] = s[c]; pq[wid][lane][c] = q[c]; }
        }
        __syncthreads();
        if (threadIdx.x < D) {
            int cgi = threadIdx.x >> 3, ci = threadIdx.x & 7;
            float t1 = ps[0][cgi][ci] + ps[1][cgi][ci] + ps[2][cgi][ci] + ps[3][cgi][ci];
            float t2 = pq[0][cgi][ci] + pq[1][cgi][ci] + pq[2][cgi][ci] + pq[3][cgi][ci];
            int cp = (blockIdx.x & 63) * 2 * D;
            atomicAdd(&tmp[cp + threadIdx.x], (double)t1);
            atomicAdd(&tmp[cp + D + threadIdx.x], (double)t2);
        }
    }
}

// ---- MFMA GEMM: Out[n][DOUT] = f(Hin)[n][DIN] @ W (+bias)(*dinv) ----
template <int DIN, int DOUT, bool BNIN, bool BIAS, bool DINVOUT, bool STATS>
__global__ __launch_bounds__(256) void mgemm_kernel(const __half* __restrict__ Hin,
                                                    const _Float16* __restrict__ Wf,
                                                    const float* __restrict__ scale,
                                                    const float* __restrict__ shift,
                                                    const float* __restrict__ bias,
                                                    const float* __restrict__ dinv,
                                                    __half* __restrict__ Out,
                                                    double* __restrict__ tmp, int n) {
    constexpr int NT = DOUT / 16;   // n-tiles per wave
    constexpr int NS = DIN / 32;    // k-steps
    constexpr int DP = DIN + 8;     // padded LDS row (halfs), keeps 16B align
    __shared__ _Float16 Hs[64 * DP];

    int node0 = blockIdx.x * 64;
    int nv = n - node0;
    if (nv > 64) nv = 64;

    constexpr int C8R = DIN / 8;
    for (int f = threadIdx.x; f < 64 * C8R; f += 256) {
        int nn = f / C8R, k8 = f - nn * C8R;
        float v[8];
        if (nn < nv) {
            load8h(Hin + (size_t)(node0 + nn) * DIN + k8 * 8, v);
        } else {
#pragma unroll
            for (int c = 0; c < 8; c++) v[c] = 0.f;
        }
        if (BNIN && nn < nv) {
            float4 sc0 = *(const float4*)(scale + k8 * 8);
            float4 sc1 = *(const float4*)(scale + k8 * 8 + 4);
            float4 sh0 = *(const float4*)(shift + k8 * 8);
            float4 sh1 = *(const float4*)(shift + k8 * 8 + 4);
            v[0] = gelu_f(fmaf(v[0], sc0.x, sh0.x));
            v[1] = gelu_f(fmaf(v[1], sc0.y, sh0.y));
            v[2] = gelu_f(fmaf(v[2], sc0.z, sh0.z));
            v[3] = gelu_f(fmaf(v[3], sc0.w, sh0.w));
            v[4] = gelu_f(fmaf(v[4], sc1.x, sh1.x));
            v[5] = gelu_f(fmaf(v[5], sc1.y, sh1.y));
            v[6] = gelu_f(fmaf(v[6], sc1.z, sh1.z));
            v[7] = gelu_f(fmaf(v[7], sc1.w, sh1.w));
        }
        f16x8 h;
#pragma unroll
        for (int c = 0; c < 8; c++) h[c] = (_Float16)v[c];
        *(f16x8*)(&Hs[nn * DP + k8 * 8]) = h;
    }
    __syncthreads();

    int wv = threadIdx.x >> 6;
    int l = threadIdx.x & 63;
    int arow = l & 15, agrp = l >> 4;

    f32x4 acc[NT];
#pragma unroll
    for (int t = 0; t < NT; t++) acc[t] = (f32x4){0.f, 0.f, 0.f, 0.f};

    const _Float16* hrow = &Hs[(wv * 16 + arow) * DP];
#pragma unroll
    for (int s = 0; s < NS; s++) {
        f16x8 a = *(const f16x8*)(hrow + s * 32 + agrp * 8);
        const _Float16* wb = Wf + (size_t)s * NT * 512 + l * 8;
#pragma unroll
        for (int t = 0; t < NT; t++) {
            f16x8 b = *(const f16x8*)(wb + (size_t)t * 512);
            acc[t] = __builtin_amdgcn_mfma_f32_16x16x32_f16(a, b, acc[t], 0, 0, 0);
        }
    }

    int rbase = wv * 16 + agrp * 4;
    float dv4[4] = {1.f, 1.f, 1.f, 1.f};
    if (DINVOUT) {
#pragma unroll
        for (int r = 0; r < 4; r++)
            if (rbase + r < nv) dv4[r] = dinv[node0 + rbase + r];
    }
    float sa[NT], qa[NT];
#pragma unroll
    for (int t = 0; t < NT; t++) {
        int col = t * 16 + arow;
        float bcol = BIAS ? bias[col] : 0.f;
        float ssum = 0.f, qsum = 0.f;
#pragma unroll
        for (int r = 0; r < 4; r++) {
            int nn = rbase + r;
            bool valid = nn < nv;
            float v = acc[t][r];
            if (DINVOUT) v *= dv4[r];
            v += bcol;
            v = valid ? v : 0.f;
            if (valid) {
                size_t oi = (size_t)(node0 + nn) * DOUT + col;
                Out[oi] = __float2half(v);
            }
            ssum += v;
            qsum += v * v;
        }
        sa[t] = ssum;
        qa[t] = qsum;
    }

    if constexpr (STATS) {
        __shared__ float ps[4][DOUT], pq[4][DOUT];
#pragma unroll
        for (int t = 0; t < NT; t++) {
            float s = sa[t], q = qa[t];
            s += __shfl_xor(s, 16, 64); q += __shfl_xor(q, 16, 64);
            s += __shfl_xor(s, 32, 64); q += __shfl_xor(q, 32, 64);
            if (l < 16) { ps[wv][t * 16 + l] = s; pq[wv][t * 16 + l] = q; }
        }
        __syncthreads();
        if (threadIdx.x < DOUT) {
            float t1 = ps[0][threadIdx.x] + ps[1][threadIdx.x] +
                       ps[2][threadIdx.x] + ps[3][threadIdx.x];
            float t2 = pq[0][threadIdx.x] + pq[1][threadIdx.x] +
                       pq[2][threadIdx.x] + pq[3][threadIdx.x];
            int cp = (blockIdx.x & 63) * 2 * DOUT;
            atomicAdd(&tmp[cp + threadIdx.x], (double)t1);
            atomicAdd(&tmp[cp + DOUT + threadIdx.x], (double)t2);
        }
    }
}

// ---- fold 64 tmp copies -> per-channel scale/shift floats ----
template <int D>
__global__ void finalize_tmp_kernel(const double* __restrict__ tmp,
                                    const float* __restrict__ g, const float* __restrict__ be,
                                    float* __restrict__ scale, float* __restrict__ shift, int n) {
    int c = threadIdx.x;
    if (c < D) {
        double s = 0.0, q = 0.0;
        for (int gg = 0; gg < 64; gg++) {
            s += tmp[gg * 2 * D + c];
            q += tmp[gg * 2 * D + D + c];
        }
        double mu = s / n;
        double var = q / n - mu * mu;
        double inv = 1.0 / sqrt(var + 1e-5);
        double sc = (double)g[c] * inv;
        scale[c] = (float)sc;
        shift[c] = (float)((double)be[c] - mu * sc);
    }
}

// ---- fold 64 tmp copies -> raw stats sums (for norm_pool) ----
template <int D>
__global__ void combine_kernel(const double* __restrict__ tmp, double* __restrict__ stats) {
    int t = threadIdx.x;
    if (t < 2 * D) {
        double s = 0.0;
        for (int gg = 0; gg < 64; gg++) s += tmp[gg * 2 * D + t];
        stats[t] = s;
    }
}

// ---- layer-3: BN normalize + GELU + mean-pool (residual handled via tmpx) ----
__global__ __launch_bounds__(256) void norm_pool_kernel(const __half* __restrict__ X3,
                                                        const double* __restrict__ stats,
                                                        const float* __restrict__ gw,
                                                        const float* __restrict__ be,
                                                        double* __restrict__ pool, int n) {
    constexpr int D = 64;
    constexpr int RPB = 4;
    int c = threadIdx.x % D;
    double mu = stats[c] / n;
    double var = stats[c + D] / n - mu * mu;
    double inv = 1.0 / sqrt(var + 1e-5);
    float scale = (float)((double)gw[c] * inv);
    float shift = (float)((double)be[c] - mu * (double)gw[c] * inv);
    int r0 = threadIdx.x / D;
    int rowsPerGrid = gridDim.x * RPB;
    double s = 0.0;
    for (int r = blockIdx.x * RPB + r0; r < n; r += rowsPerGrid) {
        size_t idx = (size_t)r * D + c;
        float t = fmaf(__half2float(X3[idx]), scale, shift);
        s += (double)gelu_f(t);
    }
    __shared__ double sh[256];
    sh[threadIdx.x] = s;
    __syncthreads();
    if (threadIdx.x < D) {
#pragma unroll
        for (int j = 1; j < RPB; j++) s += sh[threadIdx.x + j * D];
        atomicAdd(&pool[c], s);
    }
}

// ---- head MLP: 64 ->128 ->64 ->32 ->1, single block ----
__global__ __launch_bounds__(128) void mlp_kernel(const double* __restrict__ pool,
                                                  const double* __restrict__ tmpx,
                                                  const float* __restrict__ w1, const float* __restrict__ b1,
                                                  const float* __restrict__ w2, const float* __restrict__ b2,
                                                  const float* __restrict__ w3, const float* __restrict__ b3,
                                                  const float* __restrict__ w4, const float* __restrict__ b4,
                                                  float* __restrict__ out, int n) {
    __shared__ float v0[64], h1[128], h2[64], h3[32];
    int t = threadIdx.x;
    if (t < 64) {
        double px = 0.0;
        for (int gg = 0; gg < 64; gg++) px += tmpx[gg * 64 + t];
        v0[t] = (float)((pool[t] + px) / (double)n);
    }
    __syncthreads();
    if (t < 128) {
        float a = b1[t];
        for (int k = 0; k < 64; k++) a = fmaf(v0[k], w1[k * 128 + t], a);
        h1[t] = gelu_f(a);
    }
    __syncthreads();
    if (t < 64) {
        float a = b2[t];
        for (int k = 0; k < 128; k++) a = fmaf(h1[k], w2[k * 64 + t], a);
        h2[t] = gelu_f(a);
    }
    __syncthreads();
    if (t < 32) {
        float a = b3[t];
        for (int k = 0; k < 64; k++) a = fmaf(h2[k], w3[k * 32 + t], a);
        h3[t] = gelu_f(a);
    }
    __syncthreads();
    if (t == 0) {
        float a = b4[0];
        for (int k = 0; k < 32; k++) a = fmaf(h3[k], w4[k], a);
        out[0] = a;
    }
}

extern "C" void kernel_launch(void* const* d_in, const int* in_sizes, int n_in,
                              void* d_out, int out_size, void* d_ws, size_t ws_size,
                              hipStream_t stream) {
    const float* x    = (const float*)d_in[0];
    const int*   ei   = (const int*)d_in[1];
    const float* W1   = (const float*)d_in[2];
    const float* b1   = (const float*)d_in[3];
    const float* g1   = (const float*)d_in[4];
    const float* be1  = (const float*)d_in[5];
    const float* W2   = (const float*)d_in[6];
    const float* b2   = (const float*)d_in[7];
    const float* g2   = (const float*)d_in[8];
    const float* be2  = (const float*)d_in[9];
    const float* W3   = (const float*)d_in[10];
    const float* b3   = (const float*)d_in[11];
    const float* g3   = (const float*)d_in[12];
    const float* be3  = (const float*)d_in[13];
    const float* fc1w = (const float*)d_in[14];
    const float* fc1b = (const float*)d_in[15];
    const float* fc2w = (const float*)d_in[16];
    const float* fc2b = (const float*)d_in[17];
    const float* fc3w = (const float*)d_in[18];
    const float* fc3b = (const float*)d_in[19];
    const float* fc4w = (const float*)d_in[20];
    const float* fc4b = (const float*)d_in[21];

    const int N = in_sizes[0] / 64;
    const int E = in_sizes[1] / 2;
    const int* e_row = ei;       // source
    const int* e_col = ei + E;   // target (aggregation index)
    const int nbuckets = (N + 255) >> 8;

    // ---- workspace layout ----
    char* ws = (char*)d_ws;
    size_t off = 0;
    double* pool   = (double*)(ws + off); off += 64 * sizeof(double);
    double* tmp1   = (double*)(ws + off); off += 64 * 256 * sizeof(double);
    double* tmp2   = (double*)(ws + off); off += 64 * 256 * sizeof(double);
    double* tmp3   = (double*)(ws + off); off += 64 * 128 * sizeof(double);
    double* stats3 = (double*)(ws + off); off += 128 * sizeof(double);
    double* tmpx   = (double*)(ws + off); off += 64 * 64 * sizeof(double);
    const int NDBL = 64 + 64 * 256 * 2 + 64 * 128 + 128 + 64 * 64;
    float* scale1 = (float*)(ws + off); off += 128 * sizeof(float);
    float* shift1 = (float*)(ws + off); off += 128 * sizeof(float);
    float* scale2 = (float*)(ws + off); off += 128 * sizeof(float);
    float* shift2 = (float*)(ws + off); off += 128 * sizeof(float);
    _Float16* Wf1 = (_Float16*)(ws + off); off += 64 * 128 * sizeof(_Float16);
    _Float16* Wf2 = (_Float16*)(ws + off); off += 128 * 128 * sizeof(_Float16);
    _Float16* Wf3 = (_Float16*)(ws + off); off += 128 * 64 * sizeof(_Float16);
    float* deg   = (float*)(ws + off); off += (size_t)N * sizeof(float);
    float* dinv  = (float*)(ws + off); off += (size_t)N * sizeof(float);
    off = (off + 15) & ~(size_t)15;
    int* offs       = (int*)(ws + off); off += (size_t)N * sizeof(int);
    int* bucketCnt  = (int*)(ws + off); off += 512 * sizeof(int);
    int* bucketBase = (int*)(ws + off); off += 520 * sizeof(int);
    int* bcur       = (int*)(ws + off); off += 512 * sizeof(int);
    int* csr     = (int*)(ws + off); off += (size_t)E * sizeof(int);
    unsigned int* stage = (unsigned int*)(ws + off); off += (size_t)E * sizeof(unsigned int);
    off = (off + 255) & ~(size_t)255;
    __half* Ut   = (__half*)(ws + off); off += (size_t)N * 128 * sizeof(__half);  // fp16 gather table
    __half* A1   = (__half*)(ws + off); off += (size_t)N * 64 * sizeof(__half);   // agg1 out (fp16)
    __half* H    = (__half*)(ws + off); off += (size_t)N * 128 * sizeof(__half);  // fp16 features
    __half* xh   = Ut;  // alias: xh dead after agg1, before gemm2 writes Ut

    const int nb256 = (N + 255) / 256;
    const int eblk = (E + EPB - 1) / EPB;
    const int gblk = (N + 63) / 64;

    // CSR build: histogram -> scan -> stage -> finalize (deg/dinv/offs/csr)
    init_kernel<<<nb256, 256, 0, stream>>>(pool, NDBL, bucketCnt);
    coarse_count_kernel<<<eblk, 512, 0, stream>>>(e_col, bucketCnt, E, nbuckets);
    bucket_scan_kernel<<<1, 512, 0, stream>>>(bucketCnt, bucketBase, bcur, nbuckets, E);
    binstage_kernel<<<eblk, 512, 0, stream>>>(e_row, e_col, bcur, stage, E, nbuckets);
    bucket_finalize_kernel<<<nbuckets, 256, 0, stream>>>(stage, bucketBase, deg, dinv,
                                                         offs, csr, N);

    // W -> fragment-ordered fp16 (single dispatch)
    wconv_all_kernel<<<128, 256, 0, stream>>>(W1, Wf1, W2, Wf2, W3, Wf3);

    // Layer 1: x -> fp16 (dinv-scaled) + x pool sums; agg -> A1; MFMA GEMM -> H1
    halfconv_kernel<<<(N * 8 + 255) / 256, 256, 0, stream>>>(x, dinv, xh, tmpx, N);
    agg_kernel<64, false, false><<<(N + 31) / 32, 256, 0, stream>>>(
        xh, csr, offs, deg, dinv, nullptr, A1, nullptr, N);
    mgemm_kernel<64, 128, false, true, false, true><<<gblk, 256, 0, stream>>>(
        A1, Wf1, nullptr, nullptr, b1, nullptr, H, tmp1, N);
    finalize_tmp_kernel<128><<<1, 128, 0, stream>>>(tmp1, g1, be1, scale1, shift1, N);

    // Layer 2: MFMA GEMM (BN1+GELU fused, dinv prescale) -> Ut; agg -> H2 (fp16)
    mgemm_kernel<128, 128, true, false, true, false><<<gblk, 256, 0, stream>>>(
        H, Wf2, scale1, shift1, nullptr, dinv, Ut, nullptr, N);
    agg_kernel<128, true, true><<<(N + 15) / 16, 256, 0, stream>>>(
        Ut, csr, offs, deg, dinv, b2, H, tmp2, N);
    finalize_tmp_kernel<128><<<1, 128, 0, stream>>>(tmp2, g2, be2, scale2, shift2, N);

    // Layer 3: MFMA GEMM (BN2+GELU fused, dinv prescale) 128->64 -> Ut; agg -> H3
    mgemm_kernel<128, 64, true, false, true, false><<<gblk, 256, 0, stream>>>(
        H, Wf3, scale2, shift2, nullptr, dinv, Ut, nullptr, N);
    agg_kernel<64, true, true><<<(N + 31) / 32, 256, 0, stream>>>(
        Ut, csr, offs, deg, dinv, b3, H, tmp3, N);
    combine_kernel<64><<<1, 128, 0, stream>>>(tmp3, stats3);

    // Epilogue: BN3+GELU+meanpool (residual folded via tmpx), then head MLP
    norm_pool_kernel<<<1024, 256, 0, stream>>>(H, stats3, g3, be3, pool, N);
    mlp_kernel<<<1, 128, 0, stream>>>(pool, tmpx, fc1w, fc1b, fc2w, fc2b, fc3w, fc3b,
                                      fc4w, fc4b, (float*)d_out, N);
}